// Round 5
// baseline (473.884 us; speedup 1.0000x reference)
//
#include <hip/hip_runtime.h>

// TargetOpinionPairRepresentation on MI355X.
// Output row r = b*4096 + p, p = t*64 + o:
//   out[r] = concat( spans[b, target_indices[b,t]],   // 768 f32
//                    spans[b, opinion_indices[b,o]],  // 768 f32
//                    dist_emb[bucket(width)] )        // 128 f32
// width = min(|b_end - c_start|, |a_start - d_end|) from span_indices.
// bucket = searchsorted(BINS, width, right) - 1 = sum(width >= BINS[i]) - 1.
//
// R4 post-mortem: nt stores measured ~2.5 TB/s effective (kernel ~190us);
// harness fills prove ~6.3 TB/s through the normal (L2) write path.
// R5: plain stores, single-variable A/B vs R4.

#define B_DIM 16
#define S_DIM 512
#define D_DIM 768
#define E_DIM 128
#define T_DIM 64
#define O_DIM 64
#define ROW_FLOATS (2 * D_DIM + E_DIM)   // 1664
#define ROW_F4 (ROW_FLOATS / 4)          // 416
#define D_F4 (D_DIM / 4)                 // 192

typedef float f32x4 __attribute__((ext_vector_type(4)));

__global__ __launch_bounds__(256) void pair_rep_kernel(
    const float* __restrict__ spans,           // [B,S,D]
    const float* __restrict__ dist_emb,        // [14,E]
    const int*   __restrict__ span_indices,    // [S,2]
    const int*   __restrict__ target_indices,  // [B,T]
    const int*   __restrict__ opinion_indices, // [B,O]
    float*       __restrict__ out)             // [B,P,1664]
{
    const int row = blockIdx.x;          // 0 .. B*P-1
    const int b   = row >> 12;           // / 4096
    const int p   = row & 4095;
    const int t   = p >> 6;              // / 64
    const int o   = p & 63;

    const int ti = target_indices[b * T_DIM + t];
    const int oi = opinion_indices[b * O_DIM + o];

    const int a_ = span_indices[2 * ti];
    const int b_ = span_indices[2 * ti + 1];
    const int c_ = span_indices[2 * oi];
    const int d_ = span_indices[2 * oi + 1];
    const int w1 = abs(b_ - c_);
    const int w2 = abs(a_ - d_);
    const int width = min(w1, w2);

    // bucket = (# bins <= width) - 1, bins fixed
    const int bins[14] = {0, 1, 2, 3, 4, 5, 7, 8, 15, 16, 31, 32, 63, 64};
    int bucket = -1;
#pragma unroll
    for (int i = 0; i < 14; ++i) bucket += (width >= bins[i]) ? 1 : 0;

    const f32x4* st = (const f32x4*)(spans + ((size_t)b * S_DIM + ti) * D_DIM);
    const f32x4* so = (const f32x4*)(spans + ((size_t)b * S_DIM + oi) * D_DIM);
    const f32x4* de = (const f32x4*)(dist_emb + (size_t)bucket * E_DIM);
    f32x4* dst = (f32x4*)(out + (size_t)row * ROW_FLOATS);

    for (int c4 = threadIdx.x; c4 < ROW_F4; c4 += 256) {
        f32x4 v;
        if (c4 < D_F4) {
            v = st[c4];
        } else if (c4 < 2 * D_F4) {
            v = so[c4 - D_F4];
        } else {
            v = de[c4 - 2 * D_F4];
        }
        dst[c4] = v;   // plain store: stream through L2 (fills prove 6.3 TB/s this way)
    }
}

extern "C" void kernel_launch(void* const* d_in, const int* in_sizes, int n_in,
                              void* d_out, int out_size, void* d_ws, size_t ws_size,
                              hipStream_t stream) {
    const float* spans           = (const float*)d_in[0];
    const float* dist_emb        = (const float*)d_in[1];
    const int*   span_indices    = (const int*)d_in[2];
    const int*   target_indices  = (const int*)d_in[3];
    const int*   opinion_indices = (const int*)d_in[4];
    float* out = (float*)d_out;

    const int n_rows = B_DIM * T_DIM * O_DIM;  // 65536
    pair_rep_kernel<<<n_rows, 256, 0, stream>>>(
        spans, dist_emb, span_indices, target_indices, opinion_indices, out);
}

// Round 6
// 457.749 us; speedup vs baseline: 1.0352x; 1.0352x over previous
//
#include <hip/hip_runtime.h>

// TargetOpinionPairRepresentation on MI355X — R6: pair-tiled, register reuse.
//
// out[b, t*64+o] = concat(spans[b,T[b,t]] (768f), spans[b,Op[b,o]] (768f),
//                         dist_emb[bucket] (128f))
//
// R5 post-mortem: kernel ~193us for 436MB writes (~2.3 TB/s). Cause theory:
// 393MB of span-row re-reads (2 rows per output row) thrash against the
// write stream -> ~830MB mixed HBM traffic @ ~4.3 TB/s. Fix: tile 8x8 pairs
// per block; each thread owns one float4 column, loads 8 span f4 into
// registers, writes them into 64 rows. Span reads: 393MB -> ~49MB.

#define B_DIM 16
#define S_DIM 512
#define D_DIM 768
#define E_DIM 128
#define T_DIM 64
#define O_DIM 64
#define ROW_FLOATS (2 * D_DIM + E_DIM)   // 1664
#define D_F4 (D_DIM / 4)                 // 192
#define E_F4 (E_DIM / 4)                 // 32
#define TB 8
#define OB 8

typedef float f32x4 __attribute__((ext_vector_type(4)));

__global__ __launch_bounds__(448) void pair_rep_tiled(
    const float* __restrict__ spans,           // [B,S,D]
    const float* __restrict__ dist_emb,        // [14,E]
    const int*   __restrict__ span_indices,    // [S,2]
    const int*   __restrict__ target_indices,  // [B,T]
    const int*   __restrict__ opinion_indices, // [B,O]
    float*       __restrict__ out)             // [B,4096,1664]
{
    const int blk  = blockIdx.x;         // 0..1023
    const int b    = blk >> 6;
    const int tile = blk & 63;
    const int ti0  = (tile >> 3) << 3;   // target tile start (0,8,..,56)
    const int oj0  = (tile & 7) << 3;    // opinion tile start
    const int tid  = threadIdx.x;

    // Uniform per-block index loads (compiler scalarizes).
    int tidx[TB], oidx[OB];
#pragma unroll
    for (int i = 0; i < TB; ++i) tidx[i] = target_indices[b * T_DIM + ti0 + i];
#pragma unroll
    for (int j = 0; j < OB; ++j) oidx[j] = opinion_indices[b * O_DIM + oj0 + j];

    // Row base (in floats) for pair (i,j): (b*4096 + (ti0+i)*64 + oj0+j) * 1664
    const size_t row00 = ((size_t)b * 4096 + (size_t)ti0 * 64 + oj0) * ROW_FLOATS;

    if (tid < D_F4) {
        // ---- target column c4 = tid: load 8 rows' worth, write to 64 rows ----
        const int c4 = tid;
        f32x4 r[TB];
#pragma unroll
        for (int i = 0; i < TB; ++i)
            r[i] = ((const f32x4*)(spans + ((size_t)b * S_DIM + tidx[i]) * D_DIM))[c4];
#pragma unroll
        for (int i = 0; i < TB; ++i) {
            float* rowp = out + row00 + (size_t)i * 64 * ROW_FLOATS + (size_t)c4 * 4;
#pragma unroll
            for (int j = 0; j < OB; ++j)
                *(f32x4*)(rowp + (size_t)j * ROW_FLOATS) = r[i];
        }
    } else if (tid < 2 * D_F4) {
        // ---- opinion column c4 = tid-192, stored at float offset 768 ----
        const int c4 = tid - D_F4;
        f32x4 r[OB];
#pragma unroll
        for (int j = 0; j < OB; ++j)
            r[j] = ((const f32x4*)(spans + ((size_t)b * S_DIM + oidx[j]) * D_DIM))[c4];
#pragma unroll
        for (int i = 0; i < TB; ++i) {
            float* rowp = out + row00 + (size_t)i * 64 * ROW_FLOATS + D_DIM + (size_t)c4 * 4;
#pragma unroll
            for (int j = 0; j < OB; ++j)
                *(f32x4*)(rowp + (size_t)j * ROW_FLOATS) = r[j];
        }
    } else if (tid < 2 * D_F4 + E_F4) {
        // ---- dist column c = tid-384, stored at float offset 1536 ----
        const int c = tid - 2 * D_F4;
        int a_[TB], b_[TB], c_[OB], d_[OB];
#pragma unroll
        for (int i = 0; i < TB; ++i) {
            a_[i] = span_indices[2 * tidx[i]];
            b_[i] = span_indices[2 * tidx[i] + 1];
        }
#pragma unroll
        for (int j = 0; j < OB; ++j) {
            c_[j] = span_indices[2 * oidx[j]];
            d_[j] = span_indices[2 * oidx[j] + 1];
        }
        const int bins[14] = {0, 1, 2, 3, 4, 5, 7, 8, 15, 16, 31, 32, 63, 64};
#pragma unroll
        for (int i = 0; i < TB; ++i) {
            float* rowp = out + row00 + (size_t)i * 64 * ROW_FLOATS + 2 * D_DIM + (size_t)c * 4;
#pragma unroll
            for (int j = 0; j < OB; ++j) {
                const int width = min(abs(b_[i] - c_[j]), abs(a_[i] - d_[j]));
                int bucket = -1;
#pragma unroll
                for (int k = 0; k < 14; ++k) bucket += (width >= bins[k]) ? 1 : 0;
                const f32x4 v = ((const f32x4*)(dist_emb + (size_t)bucket * E_DIM))[c];
                *(f32x4*)(rowp + (size_t)j * ROW_FLOATS) = v;
            }
        }
    }
    // threads 416..447: idle pad (wave alignment)
}

extern "C" void kernel_launch(void* const* d_in, const int* in_sizes, int n_in,
                              void* d_out, int out_size, void* d_ws, size_t ws_size,
                              hipStream_t stream) {
    const float* spans           = (const float*)d_in[0];
    const float* dist_emb        = (const float*)d_in[1];
    const int*   span_indices    = (const int*)d_in[2];
    const int*   target_indices  = (const int*)d_in[3];
    const int*   opinion_indices = (const int*)d_in[4];
    float* out = (float*)d_out;

    // 16 batches x (8x8 tiles of the 64x64 pair grid) = 1024 blocks
    const int n_blocks = B_DIM * (T_DIM / TB) * (O_DIM / OB);
    pair_rep_tiled<<<n_blocks, 448, 0, stream>>>(
        spans, dist_emb, span_indices, target_indices, opinion_indices, out);
}

// Round 7
// 443.602 us; speedup vs baseline: 1.0683x; 1.0319x over previous
//
#include <hip/hip_runtime.h>

// TargetOpinionPairRepresentation on MI355X — R7: R6 + XCD swizzle + full-wave dist.
//
// out[b, t*64+o] = concat(spans[b,T[b,t]] (768f), spans[b,Op[b,o]] (768f),
//                         dist_emb[bucket] (128f))
//
// History: R4 nt-stores ~= R5 plain ~= R6 tiled+reg-reuse (-16us).
// Store micro-pattern and span re-reads are NOT the bottleneck (L3 absorbs
// reads; stores are full-line coalesced in all variants). This round probes
// the remaining floor: XCD-contiguous block mapping (span gathers become
// per-XCD L2 hits: 2 batches x 1.5MB < 4MB L2) and full lane utilization
// in the dist wave. If dur doesn't move, kernel is at its structural floor
// (~73us) and dur_us is dominated by harness poison-fill + graph overhead.

#define B_DIM 16
#define S_DIM 512
#define D_DIM 768
#define E_DIM 128
#define T_DIM 64
#define O_DIM 64
#define ROW_FLOATS (2 * D_DIM + E_DIM)   // 1664
#define D_F4 (D_DIM / 4)                 // 192
#define E_F4 (E_DIM / 4)                 // 32
#define TB 8
#define OB 8

typedef float f32x4 __attribute__((ext_vector_type(4)));

__global__ __launch_bounds__(448) void pair_rep_tiled(
    const float* __restrict__ spans,           // [B,S,D]
    const float* __restrict__ dist_emb,        // [14,E]
    const int*   __restrict__ span_indices,    // [S,2]
    const int*   __restrict__ target_indices,  // [B,T]
    const int*   __restrict__ opinion_indices, // [B,O]
    float*       __restrict__ out)             // [B,4096,1664]
{
    // XCD-bijective swizzle: hw blocks {x, x+8, x+16, ...} all land on XCD x
    // (round-robin dispatch); give them consecutive LOGICAL tiles so each XCD
    // owns a contiguous 1/8 of the output (= 2 batches -> spans L2-resident).
    const int blk0 = blockIdx.x;                 // 0..1023
    const int blk  = (blk0 & 7) * 128 + (blk0 >> 3);

    const int b    = blk >> 6;
    const int tile = blk & 63;
    const int ti0  = (tile >> 3) << 3;   // target tile start (0,8,..,56)
    const int oj0  = (tile & 7) << 3;    // opinion tile start
    const int tid  = threadIdx.x;

    // Uniform per-block index loads (compiler scalarizes).
    int tidx[TB], oidx[OB];
#pragma unroll
    for (int i = 0; i < TB; ++i) tidx[i] = target_indices[b * T_DIM + ti0 + i];
#pragma unroll
    for (int j = 0; j < OB; ++j) oidx[j] = opinion_indices[b * O_DIM + oj0 + j];

    // Row base (in floats) for pair (i,j): (b*4096 + (ti0+i)*64 + oj0+j) * 1664
    const size_t row00 = ((size_t)b * 4096 + (size_t)ti0 * 64 + oj0) * ROW_FLOATS;

    if (tid < D_F4) {
        // ---- target column c4 = tid: load 8 span f4, write to 64 rows ----
        const int c4 = tid;
        f32x4 r[TB];
#pragma unroll
        for (int i = 0; i < TB; ++i)
            r[i] = ((const f32x4*)(spans + ((size_t)b * S_DIM + tidx[i]) * D_DIM))[c4];
#pragma unroll
        for (int i = 0; i < TB; ++i) {
            float* rowp = out + row00 + (size_t)i * 64 * ROW_FLOATS + (size_t)c4 * 4;
#pragma unroll
            for (int j = 0; j < OB; ++j)
                *(f32x4*)(rowp + (size_t)j * ROW_FLOATS) = r[i];
        }
    } else if (tid < 2 * D_F4) {
        // ---- opinion column c4 = tid-192, stored at float offset 768 ----
        const int c4 = tid - D_F4;
        f32x4 r[OB];
#pragma unroll
        for (int j = 0; j < OB; ++j)
            r[j] = ((const f32x4*)(spans + ((size_t)b * S_DIM + oidx[j]) * D_DIM))[c4];
#pragma unroll
        for (int i = 0; i < TB; ++i) {
            float* rowp = out + row00 + (size_t)i * 64 * ROW_FLOATS + D_DIM + (size_t)c4 * 4;
#pragma unroll
            for (int j = 0; j < OB; ++j)
                *(f32x4*)(rowp + (size_t)j * ROW_FLOATS) = r[j];
        }
    } else {
        // ---- dist section: full wave (tid 384..447). lane&31 -> f4 column,
        //      lane>>5 -> which half of the i-loop. ----
        const int lane = tid - 2 * D_F4;     // 0..63
        const int c    = lane & 31;          // f4 column 0..31
        const int i0   = (lane >> 5) * 4;    // 0 or 4
        int a_[TB], b_[TB], c_[OB], d_[OB];
#pragma unroll
        for (int i = 0; i < TB; ++i) {
            a_[i] = span_indices[2 * tidx[i]];
            b_[i] = span_indices[2 * tidx[i] + 1];
        }
#pragma unroll
        for (int j = 0; j < OB; ++j) {
            c_[j] = span_indices[2 * oidx[j]];
            d_[j] = span_indices[2 * oidx[j] + 1];
        }
        const int bins[14] = {0, 1, 2, 3, 4, 5, 7, 8, 15, 16, 31, 32, 63, 64};
#pragma unroll
        for (int ii = 0; ii < 4; ++ii) {
            const int i = i0 + ii;
            float* rowp = out + row00 + (size_t)i * 64 * ROW_FLOATS + 2 * D_DIM + (size_t)c * 4;
#pragma unroll
            for (int j = 0; j < OB; ++j) {
                const int width = min(abs(b_[i] - c_[j]), abs(a_[i] - d_[j]));
                int bucket = -1;
#pragma unroll
                for (int k = 0; k < 14; ++k) bucket += (width >= bins[k]) ? 1 : 0;
                const f32x4 v = ((const f32x4*)(dist_emb + (size_t)bucket * E_DIM))[c];
                *(f32x4*)(rowp + (size_t)j * ROW_FLOATS) = v;
            }
        }
    }
}

extern "C" void kernel_launch(void* const* d_in, const int* in_sizes, int n_in,
                              void* d_out, int out_size, void* d_ws, size_t ws_size,
                              hipStream_t stream) {
    const float* spans           = (const float*)d_in[0];
    const float* dist_emb        = (const float*)d_in[1];
    const int*   span_indices    = (const int*)d_in[2];
    const int*   target_indices  = (const int*)d_in[3];
    const int*   opinion_indices = (const int*)d_in[4];
    float* out = (float*)d_out;

    // 16 batches x (8x8 tiles of the 64x64 pair grid) = 1024 blocks
    const int n_blocks = B_DIM * (T_DIM / TB) * (O_DIM / OB);
    pair_rep_tiled<<<n_blocks, 448, 0, stream>>>(
        spans, dist_emb, span_indices, target_indices, opinion_indices, out);
}